// Round 1
// baseline (471.976 us; speedup 1.0000x reference)
//
#include <hip/hip_runtime.h>
#include <math.h>

#define NSTEP 100
#define BATCH 16384
#define MB 32            // samples per block
#define NBLK (BATCH/MB)  // 512 blocks -> 2 blocks/CU
#define NT 256

// constants from the reference
#define C_ALPHA 0.05f
#define C_SIGMA 0.2f
#define C_THETA 0.3f
#define C_DT    0.01f
#define C_LOWER 1e-6f
#define C_PEN   100.0f
// derived drift coefficients
#define RV_T  0.015f   // A - 0.5*b_eff^2
#define RV_W  0.1f     // b_eff
#define P_T  (-0.095f) // -(ALPHA + 0.5*THETA^2)
#define P_W  (-0.3f)   // -THETA

__device__ __forceinline__ float fast_tanh(float x) {
    float e = __expf(2.0f * x);
    return 1.0f - 2.0f / (e + 1.0f);
}

// ---------------- init kernel: p0, dp0 (forward-mode tangent), pi0, zero accums ----
__global__ void init_kernel(const float* X0, const float* R0,
                            const float* pW1, const float* pb1, const float* pW2,
                            const float* pb2, const float* pW3, const float* pb3,
                            const float* qW1, const float* qb1, const float* qW2,
                            const float* qb2, const float* qW3, const float* qb3,
                            float* ws) {
    __shared__ float lh[64], ld[64];
    int j = threadIdx.x;
    float sx = X0[0], sr = R0[0];
    // ---- p-net with tangent wrt x (time input = 0 at t=0) ----
    {
        float pre = pW1[64 + j] * sx + pW1[128 + j] * sr + pb1[j];
        float h1 = fast_tanh(pre);
        float d1 = (1.0f - h1 * h1) * pW1[64 + j];
        lh[j] = h1; ld[j] = d1;
        __syncthreads();
        float pre2 = pb2[j], dpre2 = 0.0f;
        for (int i = 0; i < 64; i++) {
            float w = pW2[i * 64 + j];
            pre2 += lh[i] * w;
            dpre2 += ld[i] * w;
        }
        float h2 = fast_tanh(pre2);
        float d2 = (1.0f - h2 * h2) * dpre2;
        float c1 = h2 * pW3[j], c2 = d2 * pW3[j];
        for (int o = 32; o >= 1; o >>= 1) {
            c1 += __shfl_down(c1, o);
            c2 += __shfl_down(c2, o);
        }
        if (j == 0) { ws[0] = c1 + pb3[0]; ws[1] = c2; }
        __syncthreads();
    }
    // ---- q-net -> pi0 ----
    {
        float pre = qW1[64 + j] * sx + qW1[128 + j] * sr + qb1[j];
        float h1 = fast_tanh(pre);
        lh[j] = h1;
        __syncthreads();
        float pre2 = qb2[j];
        for (int i = 0; i < 64; i++) pre2 += lh[i] * qW2[i * 64 + j];
        float h2 = fast_tanh(pre2);
        float c1 = h2 * qW3[j];
        for (int o = 32; o >= 1; o >>= 1) c1 += __shfl_down(c1, o);
        if (j == 0) { ws[2] = c1 + qb3[0]; ws[3] = 0.0f; ws[4] = 0.0f; }
    }
}

// ---------------- main persistent scan kernel ----------------
__global__ __launch_bounds__(NT, 2) void step_kernel(
        const float* __restrict__ dw, const float* __restrict__ X0,
        const float* __restrict__ R0,
        const float* __restrict__ qW1, const float* __restrict__ qb1,
        const float* __restrict__ qW2, const float* __restrict__ qb2,
        const float* __restrict__ qW3, const float* __restrict__ qb3,
        float* __restrict__ ws, float* __restrict__ out) {
    __shared__ __align__(16) float sW2[64 * 68];  // W2[k][j] padded row 68
    __shared__ __align__(16) float sH1[MB * 65];  // H1[m][j] padded row 65
    __shared__ float sx[MB], sr[MB], spi[MB];

    const int tid = threadIdx.x;
    const int b0 = blockIdx.x * MB;

    // stage W2 in LDS (once; weights reused across all 100 steps)
    for (int u = tid; u < 64 * 64; u += NT) {
        int k = u >> 6, j = u & 63;
        sW2[k * 68 + j] = qW2[u];
    }
    const int jj = tid & 63;
    const float w1t = qW1[jj], w1x = qW1[64 + jj], w1r = qW1[128 + jj], b1 = qb1[jj];
    const int tj = tid & 15;
    const int m0 = (tid >> 4) * 2;   // 2-sample tile
    const int j0 = tj * 4;           // 4-hidden tile
    float b2r[4], w3r[4];
    #pragma unroll
    for (int u = 0; u < 4; u++) { b2r[u] = qb2[j0 + u]; w3r[u] = qW3[j0 + u]; }
    const float b3 = qb3[0];
    const float p0 = ws[0], dp0 = ws[1], pi0 = ws[2];

    const bool own = (tid < MB);
    float x = 0.f, Wsum = 0.f, minx = 0.f, R0v = 0.f;
    if (own) {
        x = X0[0]; R0v = R0[0]; minx = x;
        spi[tid] = pi0;
        size_t base = (size_t)(b0 + tid) * 5;  // row t=0
        out[base] = x; out[base + 1] = R0v; out[base + 2] = pi0;
        out[base + 3] = -p0; out[base + 4] = -dp0;
    }
    __syncthreads();

    #pragma unroll 1
    for (int i = 0; i < NSTEP - 1; i++) {
        // ---- phase 1: per-sample scalar updates (threads 0..31) ----
        if (own) {
            float dwv = dw[(size_t)(b0 + tid) * NSTEP + i];
            float pi = spi[tid];
            x = x * (1.0f + C_ALPHA * C_DT) + pi * C_SIGMA * (C_THETA * C_DT + dwv);
            minx = fminf(minx, x);
            Wsum += dwv;
            float tn = C_DT * (float)(i + 1);
            float Rv = R0v * __expf(RV_T * tn + RV_W * Wsum);
            float pm = p0 * __expf(P_T * tn + P_W * Wsum);
            sx[tid] = x; sr[tid] = Rv;
            size_t base = (size_t)((size_t)(i + 1) * BATCH + b0 + tid) * 5;
            out[base] = x; out[base + 1] = Rv;
            out[base + 3] = -pm; out[base + 4] = -dp0;
        }
        __syncthreads();  // B1: x,Rv visible

        // ---- phase 2: H1 = tanh(W1 @ st) ----
        {
            float c0 = w1t * (2.0f * C_DT * (float)(i + 1)) + b1;
            int mbase = (tid >> 6) * 8;
            #pragma unroll
            for (int mm = 0; mm < 8; mm++) {
                int m = mbase + mm;
                float h = fast_tanh(c0 + w1x * sx[m] + w1r * sr[m]);
                sH1[m * 65 + jj] = h;
            }
        }
        __syncthreads();  // B2: H1 visible

        // ---- phase 3: H2 = tanh(H1 @ W2 + b2), then pi = tanh-free layer-3 ----
        float a00 = b2r[0], a01 = b2r[1], a02 = b2r[2], a03 = b2r[3];
        float a10 = b2r[0], a11 = b2r[1], a12 = b2r[2], a13 = b2r[3];
        #pragma unroll 8
        for (int k = 0; k < 64; k++) {
            float av0 = sH1[m0 * 65 + k];
            float av1 = sH1[(m0 + 1) * 65 + k];
            float4 bv = *reinterpret_cast<const float4*>(&sW2[k * 68 + j0]);
            a00 += av0 * bv.x; a01 += av0 * bv.y; a02 += av0 * bv.z; a03 += av0 * bv.w;
            a10 += av1 * bv.x; a11 += av1 * bv.y; a12 += av1 * bv.z; a13 += av1 * bv.w;
        }
        float o0 = fast_tanh(a00) * w3r[0] + fast_tanh(a01) * w3r[1] +
                   fast_tanh(a02) * w3r[2] + fast_tanh(a03) * w3r[3];
        float o1 = fast_tanh(a10) * w3r[0] + fast_tanh(a11) * w3r[1] +
                   fast_tanh(a12) * w3r[2] + fast_tanh(a13) * w3r[3];
        #pragma unroll
        for (int o = 8; o >= 1; o >>= 1) {
            o0 += __shfl_xor(o0, o);
            o1 += __shfl_xor(o1, o);
        }
        if (tj == 0) {
            float pn0 = o0 + b3, pn1 = o1 + b3;
            spi[m0] = pn0; spi[m0 + 1] = pn1;
            size_t base = (size_t)((size_t)(i + 1) * BATCH + b0) * 5;
            out[base + (size_t)m0 * 5 + 2] = pn0;
            out[base + (size_t)(m0 + 1) * 5 + 2] = pn1;
        }
        __syncthreads();  // B3: pi visible for next step
    }

    // ---- final step i=99: no pi update (upd mask false), then losses ----
    if (own) {
        float dwv = dw[(size_t)(b0 + tid) * NSTEP + (NSTEP - 1)];
        float pi = spi[tid];
        x = x * (1.0f + C_ALPHA * C_DT) + pi * C_SIGMA * (C_THETA * C_DT + dwv);
        minx = fminf(minx, x);
        Wsum += dwv;
        float tn = 1.0f;
        float Rf = R0v * __expf(RV_T * tn + RV_W * Wsum);
        float pf = p0 * __expf(P_T * tn + P_W * Wsum);
        size_t base = (size_t)((size_t)NSTEP * BATCH + b0 + tid) * 5;
        out[base] = x; out[base + 1] = Rf; out[base + 2] = pi;
        out[base + 3] = -pf; out[base + 4] = -dp0;

        float xc = fmaxf(x, C_LOWER);
        float ux = Rf * rsqrtf(xc);            // R * xc^(gamma-1), gamma=0.5
        float uval = 2.0f * Rf * sqrtf(xc);    // R * xc^gamma / gamma
        float d = fmaxf(C_LOWER - minx, 0.0f);
        float pen = C_PEN * d * d;
        float t1 = pf + ux;
        float v1 = t1 * t1 + pen;
        float v2 = -uval + pen;
        #pragma unroll
        for (int o = 16; o >= 1; o >>= 1) {
            v1 += __shfl_down(v1, o);
            v2 += __shfl_down(v2, o);
        }
        if (tid == 0) {
            atomicAdd(&ws[3], v1);
            atomicAdd(&ws[4], v2);
        }
    }
}

// ---------------- finalize losses ----------------
__global__ void fin_kernel(const float* ws, float* out) {
    float lp = ws[3] * (1.0f / (float)BATCH);
    float lq = ws[4] * (1.0f / (float)BATCH);
    out[(size_t)(NSTEP + 1) * BATCH * 5] = lp;
    out[(size_t)(NSTEP + 1) * BATCH * 5 + 1] = lp + lq;
}

extern "C" void kernel_launch(void* const* d_in, const int* in_sizes, int n_in,
                              void* d_out, int out_size, void* d_ws, size_t ws_size,
                              hipStream_t stream) {
    const float* dw  = (const float*)d_in[0];
    const float* X0  = (const float*)d_in[1];
    const float* R0  = (const float*)d_in[2];
    const float* pW1 = (const float*)d_in[3];
    const float* pb1 = (const float*)d_in[4];
    const float* pW2 = (const float*)d_in[5];
    const float* pb2 = (const float*)d_in[6];
    const float* pW3 = (const float*)d_in[7];
    const float* pb3 = (const float*)d_in[8];
    const float* qW1 = (const float*)d_in[9];
    const float* qb1 = (const float*)d_in[10];
    const float* qW2 = (const float*)d_in[11];
    const float* qb2 = (const float*)d_in[12];
    const float* qW3 = (const float*)d_in[13];
    const float* qb3 = (const float*)d_in[14];
    float* out = (float*)d_out;
    float* ws  = (float*)d_ws;

    init_kernel<<<1, 64, 0, stream>>>(X0, R0, pW1, pb1, pW2, pb2, pW3, pb3,
                                      qW1, qb1, qW2, qb2, qW3, qb3, ws);
    step_kernel<<<NBLK, NT, 0, stream>>>(dw, X0, R0, qW1, qb1, qW2, qb2, qW3, qb3,
                                         ws, out);
    fin_kernel<<<1, 1, 0, stream>>>(ws, out);
}

// Round 2
// 233.478 us; speedup vs baseline: 2.0215x; 2.0215x over previous
//
#include <hip/hip_runtime.h>
#include <math.h>

#define NSTEP 100
#define BATCH 16384
#define MB 32            // samples per block
#define NBLK (BATCH/MB)  // 512 blocks -> 2 blocks/CU
#define NT 256

// constants from the reference
#define C_ALPHA 0.05f
#define C_SIGMA 0.2f
#define C_THETA 0.3f
#define C_DT    0.01f
#define C_LOWER 1e-6f
#define C_PEN   100.0f
// derived drift coefficients
#define RV_T  0.015f   // A - 0.5*b_eff^2
#define RV_W  0.1f     // b_eff
#define P_T  (-0.095f) // -(ALPHA + 0.5*THETA^2)
#define P_W  (-0.3f)   // -THETA

typedef __attribute__((ext_vector_type(8))) short bf16x8;
typedef __attribute__((ext_vector_type(4))) float f32x4;

// tanh via v_exp + v_rcp (no full-precision divide sequence)
__device__ __forceinline__ float fast_tanh(float x) {
    float e = __builtin_amdgcn_exp2f(x * 2.885390082f);   // exp(2x)
    return 1.0f - 2.0f * __builtin_amdgcn_rcpf(e + 1.0f);
}
// fp32 -> bf16 bits, round-to-nearest-even
__device__ __forceinline__ unsigned short f2bf(float f) {
    unsigned u = __float_as_uint(f);
    return (unsigned short)((u + 0x7FFFu + ((u >> 16) & 1u)) >> 16);
}

// ---------------- init kernel: p0, dp0 (forward-mode tangent), pi0, zero accums ----
__global__ void init_kernel(const float* X0, const float* R0,
                            const float* pW1, const float* pb1, const float* pW2,
                            const float* pb2, const float* pW3, const float* pb3,
                            const float* qW1, const float* qb1, const float* qW2,
                            const float* qb2, const float* qW3, const float* qb3,
                            float* ws) {
    __shared__ float lh[64], ld[64];
    int j = threadIdx.x;
    float sx = X0[0], sr = R0[0];
    // ---- p-net with tangent wrt x (time input = 0 at t=0) ----
    {
        float pre = pW1[64 + j] * sx + pW1[128 + j] * sr + pb1[j];
        float h1 = fast_tanh(pre);
        float d1 = (1.0f - h1 * h1) * pW1[64 + j];
        lh[j] = h1; ld[j] = d1;
        __syncthreads();
        float pre2 = pb2[j], dpre2 = 0.0f;
        for (int i = 0; i < 64; i++) {
            float w = pW2[i * 64 + j];
            pre2 += lh[i] * w;
            dpre2 += ld[i] * w;
        }
        float h2 = fast_tanh(pre2);
        float d2 = (1.0f - h2 * h2) * dpre2;
        float c1 = h2 * pW3[j], c2 = d2 * pW3[j];
        for (int o = 32; o >= 1; o >>= 1) {
            c1 += __shfl_down(c1, o);
            c2 += __shfl_down(c2, o);
        }
        if (j == 0) { ws[0] = c1 + pb3[0]; ws[1] = c2; }
        __syncthreads();
    }
    // ---- q-net -> pi0 ----
    {
        float pre = qW1[64 + j] * sx + qW1[128 + j] * sr + qb1[j];
        float h1 = fast_tanh(pre);
        lh[j] = h1;
        __syncthreads();
        float pre2 = qb2[j];
        for (int i = 0; i < 64; i++) pre2 += lh[i] * qW2[i * 64 + j];
        float h2 = fast_tanh(pre2);
        float c1 = h2 * qW3[j];
        for (int o = 32; o >= 1; o >>= 1) c1 += __shfl_down(c1, o);
        if (j == 0) { ws[2] = c1 + qb3[0]; ws[3] = 0.0f; ws[4] = 0.0f; }
    }
}

// ---------------- main persistent scan kernel (bf16 MFMA layer-2) ----------------
__global__ __launch_bounds__(NT, 2) void step_kernel(
        const float* __restrict__ dw, const float* __restrict__ X0,
        const float* __restrict__ R0,
        const float* __restrict__ qW1, const float* __restrict__ qb1,
        const float* __restrict__ qW2, const float* __restrict__ qb2,
        const float* __restrict__ qW3, const float* __restrict__ qb3,
        float* __restrict__ ws, float* __restrict__ out) {
    // W2^T bf16 [n][k], row stride 72 (144 B: 16B-aligned, bank stride 36%32=4 -> 2-way max)
    __shared__ __align__(16) unsigned short sW2T[64 * 72];
    // H1 bf16 [m][k], row stride 72
    __shared__ __align__(16) unsigned short sH1[MB * 72];
    __shared__ float sx[MB], sr[MB];
    __shared__ __align__(16) float sP[2][MB];   // layer-3 partials per N-half

    const int tid = threadIdx.x;
    const int b0 = blockIdx.x * MB;
    const int lane = tid & 63;
    const int wv = tid >> 6;          // wave 0..3
    const int mt = wv & 1;            // M-tile (16 samples)
    const int nh = wv >> 1;           // N-half (32 of 64 hidden)
    const int l15 = lane & 15, quad = lane >> 4;

    // stage W2^T as bf16 (once; reused 100 steps)
    for (int u = tid; u < 64 * 64; u += NT) {
        int k = u >> 6, n = u & 63;       // qW2 is [k][n] row-major
        sW2T[n * 72 + k] = f2bf(qW2[u]);
    }
    // layer-1 per-thread consts (thread -> hidden j = tid&63, 8 samples)
    const int jj = tid & 63;
    const int mg = tid >> 6;
    const float w1t = qW1[jj], w1x = qW1[64 + jj], w1r = qW1[128 + jj], b1 = qb1[jj];
    // per-lane layer-2/3 consts: this lane's two output columns n0, n1
    const int n0 = nh * 32 + l15;
    const int n1 = n0 + 16;
    const float b2v0 = qb2[n0], b2v1 = qb2[n1];
    const float w3v0 = qW3[n0], w3v1 = qW3[n1];
    const float b3 = qb3[0];
    const float p0 = ws[0], dp0 = ws[1], pi0 = ws[2];
    __syncthreads();   // sW2T visible

    // preload loop-invariant B fragments: B[k][n], lane: n=l15-col, k=quad*8+j
    bf16x8 Bf00 = *(const bf16x8*)&sW2T[n0 * 72 + quad * 8];        // kstep 0, ntile 0
    bf16x8 Bf10 = *(const bf16x8*)&sW2T[n0 * 72 + 32 + quad * 8];   // kstep 1, ntile 0
    bf16x8 Bf01 = *(const bf16x8*)&sW2T[n1 * 72 + quad * 8];        // kstep 0, ntile 1
    bf16x8 Bf11 = *(const bf16x8*)&sW2T[n1 * 72 + 32 + quad * 8];   // kstep 1, ntile 1

    const bool own = (tid < MB);
    float x = 0.f, Wsum = 0.f, minx = 0.f, R0v = 0.f, pi = 0.f;
    if (own) {
        x = X0[0]; R0v = R0[0]; minx = x; pi = pi0;
        size_t base = (size_t)(b0 + tid) * 5;  // row t=0
        out[base] = x; out[base + 1] = R0v; out[base + 2] = pi0;
        out[base + 3] = -p0; out[base + 4] = -dp0;
    }

    #pragma unroll 1
    for (int i = 0; i < NSTEP - 1; i++) {
        // ---- phase 0+1: owner assembles prev-step pi, then scalar updates ----
        if (own) {
            int m = tid;
            if (i > 0) {
                pi = sP[0][m] + sP[1][m] + b3;                       // step i-1 GEMM result
                out[((size_t)i * BATCH + b0 + m) * 5 + 2] = pi;     // row i's pi
            }
            float dwv = dw[(size_t)(b0 + m) * NSTEP + i];
            x = x * (1.0f + C_ALPHA * C_DT) + pi * C_SIGMA * (C_THETA * C_DT + dwv);
            minx = fminf(minx, x);
            Wsum += dwv;
            float tn = C_DT * (float)(i + 1);
            float Rv = R0v * __expf(RV_T * tn + RV_W * Wsum);
            float pm = p0 * __expf(P_T * tn + P_W * Wsum);
            sx[m] = x; sr[m] = Rv;
            size_t base = ((size_t)(i + 1) * BATCH + b0 + m) * 5;
            out[base] = x; out[base + 1] = Rv;
            out[base + 3] = -pm; out[base + 4] = -dp0;
        }
        __syncthreads();  // B_a: sx,sr visible

        // ---- phase 2: H1 = tanh(W1 @ st) -> bf16 LDS, A-fragment layout ----
        {
            float c0 = w1t * (2.0f * C_DT * (float)(i + 1)) + b1;
            #pragma unroll
            for (int mm = 0; mm < 8; mm++) {
                int m = mg * 8 + mm;
                float h = fast_tanh(c0 + w1x * sx[m] + w1r * sr[m]);
                sH1[m * 72 + jj] = f2bf(h);
            }
        }
        __syncthreads();  // B_b: H1 visible

        // ---- phase 3: MFMA layer-2, tanh, layer-3 partial reduce ----
        const unsigned short* arow = &sH1[(mt * 16 + l15) * 72 + quad * 8];
        bf16x8 A0 = *(const bf16x8*)arow;         // kstep 0
        bf16x8 A1 = *(const bf16x8*)(arow + 32);  // kstep 1
        f32x4 acc0 = {b2v0, b2v0, b2v0, b2v0};
        f32x4 acc1 = {b2v1, b2v1, b2v1, b2v1};
        acc0 = __builtin_amdgcn_mfma_f32_16x16x32_bf16(A0, Bf00, acc0, 0, 0, 0);
        acc0 = __builtin_amdgcn_mfma_f32_16x16x32_bf16(A1, Bf10, acc0, 0, 0, 0);
        acc1 = __builtin_amdgcn_mfma_f32_16x16x32_bf16(A0, Bf01, acc1, 0, 0, 0);
        acc1 = __builtin_amdgcn_mfma_f32_16x16x32_bf16(A1, Bf11, acc1, 0, 0, 0);
        f32x4 part;
        #pragma unroll
        for (int r = 0; r < 4; r++)
            part[r] = fast_tanh(acc0[r]) * w3v0 + fast_tanh(acc1[r]) * w3v1;
        #pragma unroll
        for (int o = 1; o < 16; o <<= 1) {   // reduce over the 16 columns (lane&15)
            part[0] += __shfl_xor(part[0], o);
            part[1] += __shfl_xor(part[1], o);
            part[2] += __shfl_xor(part[2], o);
            part[3] += __shfl_xor(part[3], o);
        }
        if (l15 == 0)   // rows m = mt*16 + quad*4 + r
            *(f32x4*)&sP[nh][mt * 16 + quad * 4] = part;
        __syncthreads();  // B_c: partials visible for next step's phase 0
    }

    // ---- final step i=99: assemble step-98 pi, no pi update, losses ----
    if (own) {
        int m = tid;
        pi = sP[0][m] + sP[1][m] + b3;                                  // step-98 pi_new
        out[((size_t)(NSTEP - 1) * BATCH + b0 + m) * 5 + 2] = pi;       // row 99
        float dwv = dw[(size_t)(b0 + m) * NSTEP + (NSTEP - 1)];
        x = x * (1.0f + C_ALPHA * C_DT) + pi * C_SIGMA * (C_THETA * C_DT + dwv);
        minx = fminf(minx, x);
        Wsum += dwv;
        float Rf = R0v * __expf(RV_T * 1.0f + RV_W * Wsum);
        float pf = p0 * __expf(P_T * 1.0f + P_W * Wsum);
        size_t base = ((size_t)NSTEP * BATCH + b0 + m) * 5;
        out[base] = x; out[base + 1] = Rf; out[base + 2] = pi;   // row 100 keeps old pi
        out[base + 3] = -pf; out[base + 4] = -dp0;

        float xc = fmaxf(x, C_LOWER);
        float ux = Rf * rsqrtf(xc);            // R * xc^(gamma-1), gamma=0.5
        float uval = 2.0f * Rf * sqrtf(xc);    // R * xc^gamma / gamma
        float d = fmaxf(C_LOWER - minx, 0.0f);
        float pen = C_PEN * d * d;
        float t1 = pf + ux;
        float v1 = t1 * t1 + pen;
        float v2 = -uval + pen;
        #pragma unroll
        for (int o = 16; o >= 1; o >>= 1) {
            v1 += __shfl_down(v1, o);
            v2 += __shfl_down(v2, o);
        }
        if (tid == 0) {
            atomicAdd(&ws[3], v1);
            atomicAdd(&ws[4], v2);
        }
    }
}

// ---------------- finalize losses ----------------
__global__ void fin_kernel(const float* ws, float* out) {
    float lp = ws[3] * (1.0f / (float)BATCH);
    float lq = ws[4] * (1.0f / (float)BATCH);
    out[(size_t)(NSTEP + 1) * BATCH * 5] = lp;
    out[(size_t)(NSTEP + 1) * BATCH * 5 + 1] = lp + lq;
}

extern "C" void kernel_launch(void* const* d_in, const int* in_sizes, int n_in,
                              void* d_out, int out_size, void* d_ws, size_t ws_size,
                              hipStream_t stream) {
    const float* dw  = (const float*)d_in[0];
    const float* X0  = (const float*)d_in[1];
    const float* R0  = (const float*)d_in[2];
    const float* pW1 = (const float*)d_in[3];
    const float* pb1 = (const float*)d_in[4];
    const float* pW2 = (const float*)d_in[5];
    const float* pb2 = (const float*)d_in[6];
    const float* pW3 = (const float*)d_in[7];
    const float* pb3 = (const float*)d_in[8];
    const float* qW1 = (const float*)d_in[9];
    const float* qb1 = (const float*)d_in[10];
    const float* qW2 = (const float*)d_in[11];
    const float* qb2 = (const float*)d_in[12];
    const float* qW3 = (const float*)d_in[13];
    const float* qb3 = (const float*)d_in[14];
    float* out = (float*)d_out;
    float* ws  = (float*)d_ws;

    init_kernel<<<1, 64, 0, stream>>>(X0, R0, pW1, pb1, pW2, pb2, pW3, pb3,
                                      qW1, qb1, qW2, qb2, qW3, qb3, ws);
    step_kernel<<<NBLK, NT, 0, stream>>>(dw, X0, R0, qW1, qb1, qW2, qb2, qW3, qb3,
                                         ws, out);
    fin_kernel<<<1, 1, 0, stream>>>(ws, out);
}

// Round 3
// 228.966 us; speedup vs baseline: 2.0613x; 1.0197x over previous
//
#include <hip/hip_runtime.h>
#include <math.h>

#define NSTEP 100
#define BATCH 16384
#define MB 16            // samples per block == MFMA M
#define NBLK (BATCH/MB)  // 1024 single-wave blocks -> 4/CU, 1 wave/SIMD
#define NT 64

// constants from the reference
#define C_ALPHA 0.05f
#define C_SIGMA 0.2f
#define C_THETA 0.3f
#define C_DT    0.01f
#define C_LOWER 1e-6f
#define C_PEN   100.0f
#define LOG2E   1.4426950408889634f
#define TSCALE  (2.0f * LOG2E)      // tanh(z) = 1 - 2/(exp2(TSCALE*z)+1)
// exp2-folded drift coefficients (fi = i+1, tn = fi*DT)
#define CRT ( 0.015f * C_DT * LOG2E)   // (A - 0.5 b^2) * dt * log2e
#define CRW ( 0.1f * LOG2E)            // b * log2e
#define CPT (-0.095f * C_DT * LOG2E)   // -(alpha+0.5 theta^2) * dt * log2e
#define CPW (-0.3f * LOG2E)            // -theta * log2e

typedef __attribute__((ext_vector_type(8))) short bf16x8;
typedef __attribute__((ext_vector_type(4))) float f32x4;

// tanh(z) given zs = TSCALE*z (scale pre-folded into weights)
__device__ __forceinline__ float tanh_pre(float zs) {
    float e = __builtin_amdgcn_exp2f(zs);
    return 1.0f - 2.0f * __builtin_amdgcn_rcpf(e + 1.0f);
}
// fp32 -> bf16 bits, RNE
__device__ __forceinline__ unsigned f2bf_u(float f) {
    unsigned u = __float_as_uint(f);
    return (u + 0x7FFFu + ((u >> 16) & 1u)) >> 16;
}

// ---------------- init: p0, dp0 (fwd tangent), pi0; zero accumulators ----------
__global__ void init_kernel(const float* X0, const float* R0,
                            const float* pW1, const float* pb1, const float* pW2,
                            const float* pb2, const float* pW3, const float* pb3,
                            const float* qW1, const float* qb1, const float* qW2,
                            const float* qb2, const float* qW3, const float* qb3,
                            float* ws) {
    __shared__ float sw[2][4096];
    int tid = threadIdx.x;
    for (int u = tid; u < 4096; u += 256) { sw[0][u] = pW2[u]; sw[1][u] = qW2[u]; }
    __syncthreads();
    int wv = tid >> 6, j = tid & 63;
    float sx = X0[0], sr = R0[0];
    if (wv == 0) {           // p-net + x-tangent
        float pre = pW1[64 + j] * sx + pW1[128 + j] * sr + pb1[j];
        float h1 = tanh_pre(TSCALE * pre);
        float d1 = (1.0f - h1 * h1) * pW1[64 + j];
        float pre2 = pb2[j], dpre2 = 0.0f;
        #pragma unroll 8
        for (int i2 = 0; i2 < 64; i2++) {
            float w = sw[0][i2 * 64 + j];
            pre2  += __shfl(h1, i2) * w;
            dpre2 += __shfl(d1, i2) * w;
        }
        float h2 = tanh_pre(TSCALE * pre2);
        float d2 = (1.0f - h2 * h2) * dpre2;
        float c1 = h2 * pW3[j], c2 = d2 * pW3[j];
        for (int o = 32; o >= 1; o >>= 1) {
            c1 += __shfl_down(c1, o); c2 += __shfl_down(c2, o);
        }
        if (j == 0) { ws[0] = c1 + pb3[0]; ws[1] = c2; }
    } else if (wv == 1) {    // q-net -> pi0
        float pre = qW1[64 + j] * sx + qW1[128 + j] * sr + qb1[j];
        float h1 = tanh_pre(TSCALE * pre);
        float pre2 = qb2[j];
        #pragma unroll 8
        for (int i2 = 0; i2 < 64; i2++) pre2 += __shfl(h1, i2) * sw[1][i2 * 64 + j];
        float h2 = tanh_pre(TSCALE * pre2);
        float c1 = h2 * qW3[j];
        for (int o = 32; o >= 1; o >>= 1) c1 += __shfl_down(c1, o);
        if (j == 0) { ws[2] = c1 + qb3[0]; ws[3] = 0.0f; ws[4] = 0.0f; ws[5] = 0.0f; }
    }
}

// ---------------- main: single-wave persistent scan, no barriers ----------------
__global__ __launch_bounds__(NT, 1) void step_kernel(
        const float* __restrict__ dw, const float* __restrict__ X0,
        const float* __restrict__ R0,
        const float* __restrict__ qW1, const float* __restrict__ qb1,
        const float* __restrict__ qW2, const float* __restrict__ qb2,
        const float* __restrict__ qW3, const float* __restrict__ qb3,
        float* __restrict__ ws, float* __restrict__ out) {
    __shared__ __align__(16) unsigned short sW2T[64 * 72];  // bf16 W2^T [n][k], *TSCALE
    __shared__ __align__(16) float sdw[MB * NSTEP];
    __shared__ __align__(16) float sPi[MB];

    const int lane = threadIdx.x;          // one wave
    const int b0 = blockIdx.x * MB;
    const int l15 = lane & 15, quad = lane >> 4;

    // stage dw (contiguous 1600 floats, coalesced float4)
    {
        const float4* g = (const float4*)(dw + (size_t)b0 * NSTEP);
        float4* s = (float4*)sdw;
        #pragma unroll
        for (int u = lane; u < MB * NSTEP / 4; u += NT) s[u] = g[u];
    }
    // stage W2^T bf16 (pre-scaled); global coalesced, one-time LDS write conflicts ok
    #pragma unroll 8
    for (int t = 0; t < 64; t++) {
        float w = qW2[t * 64 + lane];                 // row t, col lane
        sW2T[lane * 72 + t] = (unsigned short)f2bf_u(w * TSCALE);
    }
    // resident B fragments: 4 n-tiles x 2 k-steps
    bf16x8 Bf[4][2];
    #pragma unroll
    for (int nt = 0; nt < 4; nt++) {
        const unsigned short* r = &sW2T[(nt * 16 + l15) * 72 + quad * 8];
        Bf[nt][0] = *(const bf16x8*)r;
        Bf[nt][1] = *(const bf16x8*)(r + 32);
    }
    // layer-1 consts for this lane's 16 k's (idx<8: kstep0, else kstep1)
    float tco[16], w1xs[16], w1rs[16], b1s[16];
    #pragma unroll
    for (int idx = 0; idx < 16; idx++) {
        int k = (idx < 8) ? (quad * 8 + idx) : (32 + quad * 8 + (idx - 8));
        tco[idx]  = qW1[k] * (2.0f * C_DT * TSCALE);
        w1xs[idx] = qW1[64 + k] * TSCALE;
        w1rs[idx] = qW1[128 + k] * TSCALE;
        b1s[idx]  = qb1[k] * TSCALE;
    }
    float b2v[4], w3v[4];
    #pragma unroll
    for (int nt = 0; nt < 4; nt++) {
        b2v[nt] = qb2[nt * 16 + l15] * TSCALE;
        w3v[nt] = qW3[nt * 16 + l15];
    }
    const float b3 = qb3[0];
    const float p0 = ws[0], dp0 = ws[1], pi0 = ws[2];
    const float X0v = X0[0], R0s = R0[0];

    float x = 0.f, Wsum = 0.f, minx = 0.f, R0v = 0.f, pi = 0.f;
    float v1 = 0.f, v2 = 0.f;
    if (lane < MB) {
        x = X0v; R0v = R0s; minx = x; pi = pi0;
        sPi[lane] = pi0;
        size_t base = (size_t)(b0 + lane) * 5;
        out[base] = x; out[base + 1] = R0v; out[base + 2] = pi0;
        out[base + 3] = -p0; out[base + 4] = -dp0;
    }

    #pragma unroll 1
    for (int i = 0; i < NSTEP - 1; i++) {
        float fi = (float)(i + 1);
        float Rcur = 0.f;
        if (lane < MB) {
            pi = sPi[lane];
            float dwv = sdw[lane * NSTEP + i];
            x = x * (1.0f + C_ALPHA * C_DT) + pi * C_SIGMA * (C_THETA * C_DT + dwv);
            minx = fminf(minx, x);
            Wsum += dwv;
            Rcur = R0v * __builtin_amdgcn_exp2f(fmaf(CRW, Wsum, CRT * fi));
            float pm = p0 * __builtin_amdgcn_exp2f(fmaf(CPW, Wsum, CPT * fi));
            size_t base = ((size_t)(i + 1) * BATCH + b0 + lane) * 5;
            out[base] = x; out[base + 1] = Rcur;
            out[base + 3] = -pm; out[base + 4] = -dp0;
        }
        // broadcast this lane's sample state (row m = l15)
        float xb = __shfl(x, l15);
        float rb = __shfl(Rcur, l15);

        // H1 directly into A fragments (no LDS round-trip)
        union { bf16x8 v; unsigned u[4]; } A0, A1;
        #pragma unroll
        for (int p = 0; p < 8; p++) {
            int i0 = 2 * p, i1 = 2 * p + 1;
            float z0 = fmaf(w1rs[i0], rb, fmaf(w1xs[i0], xb, fmaf(tco[i0], fi, b1s[i0])));
            float z1 = fmaf(w1rs[i1], rb, fmaf(w1xs[i1], xb, fmaf(tco[i1], fi, b1s[i1])));
            unsigned pk = f2bf_u(tanh_pre(z0)) | (f2bf_u(tanh_pre(z1)) << 16);
            if (p < 4) A0.u[p] = pk; else A1.u[p - 4] = pk;
        }
        // layer-2 MFMA (W2,b2 pre-scaled by TSCALE) + tanh + layer-3 combine
        f32x4 part;
        {
            f32x4 acc0 = {b2v[0], b2v[0], b2v[0], b2v[0]};
            f32x4 acc1 = {b2v[1], b2v[1], b2v[1], b2v[1]};
            f32x4 acc2 = {b2v[2], b2v[2], b2v[2], b2v[2]};
            f32x4 acc3 = {b2v[3], b2v[3], b2v[3], b2v[3]};
            acc0 = __builtin_amdgcn_mfma_f32_16x16x32_bf16(A0.v, Bf[0][0], acc0, 0, 0, 0);
            acc1 = __builtin_amdgcn_mfma_f32_16x16x32_bf16(A0.v, Bf[1][0], acc1, 0, 0, 0);
            acc2 = __builtin_amdgcn_mfma_f32_16x16x32_bf16(A0.v, Bf[2][0], acc2, 0, 0, 0);
            acc3 = __builtin_amdgcn_mfma_f32_16x16x32_bf16(A0.v, Bf[3][0], acc3, 0, 0, 0);
            acc0 = __builtin_amdgcn_mfma_f32_16x16x32_bf16(A1.v, Bf[0][1], acc0, 0, 0, 0);
            acc1 = __builtin_amdgcn_mfma_f32_16x16x32_bf16(A1.v, Bf[1][1], acc1, 0, 0, 0);
            acc2 = __builtin_amdgcn_mfma_f32_16x16x32_bf16(A1.v, Bf[2][1], acc2, 0, 0, 0);
            acc3 = __builtin_amdgcn_mfma_f32_16x16x32_bf16(A1.v, Bf[3][1], acc3, 0, 0, 0);
            #pragma unroll
            for (int r = 0; r < 4; r++) {
                float s = tanh_pre(acc0[r]) * w3v[0];
                s = fmaf(tanh_pre(acc1[r]), w3v[1], s);
                s = fmaf(tanh_pre(acc2[r]), w3v[2], s);
                s = fmaf(tanh_pre(acc3[r]), w3v[3], s);
                part[r] = s;
            }
        }
        // reduce over the 16 columns (lanes sharing a quad)
        #pragma unroll
        for (int o = 1; o < 16; o <<= 1) {
            part[0] += __shfl_xor(part[0], o);
            part[1] += __shfl_xor(part[1], o);
            part[2] += __shfl_xor(part[2], o);
            part[3] += __shfl_xor(part[3], o);
        }
        if (l15 == 0) {   // rows quad*4 + r
            float q0 = part[0] + b3, q1 = part[1] + b3;
            float q2 = part[2] + b3, q3 = part[3] + b3;
            f32x4 pv = {q0, q1, q2, q3};
            *(f32x4*)&sPi[quad * 4] = pv;
            size_t base = ((size_t)(i + 1) * BATCH + b0 + quad * 4) * 5 + 2;
            out[base] = q0; out[base + 5] = q1; out[base + 10] = q2; out[base + 15] = q3;
        }
    }

    // ---- final step i=99 (pi not updated) + losses ----
    if (lane < MB) {
        pi = sPi[lane];
        float dwv = sdw[lane * NSTEP + (NSTEP - 1)];
        x = x * (1.0f + C_ALPHA * C_DT) + pi * C_SIGMA * (C_THETA * C_DT + dwv);
        minx = fminf(minx, x);
        Wsum += dwv;
        float Rf = R0v * __builtin_amdgcn_exp2f(fmaf(CRW, Wsum, CRT * (float)NSTEP));
        float pf = p0 * __builtin_amdgcn_exp2f(fmaf(CPW, Wsum, CPT * (float)NSTEP));
        size_t base = ((size_t)NSTEP * BATCH + b0 + lane) * 5;
        out[base] = x; out[base + 1] = Rf; out[base + 2] = pi;
        out[base + 3] = -pf; out[base + 4] = -dp0;

        float xc = fmaxf(x, C_LOWER);
        float ux = Rf * rsqrtf(xc);           // R * xc^(gamma-1), gamma=0.5
        float uval = 2.0f * Rf * sqrtf(xc);   // R * xc^gamma / gamma
        float d = fmaxf(C_LOWER - minx, 0.0f);
        float pen = C_PEN * d * d;
        float t1 = pf + ux;
        v1 = t1 * t1 + pen;
        v2 = -uval + pen;
    }
    #pragma unroll
    for (int o = 8; o >= 1; o >>= 1) {
        v1 += __shfl_down(v1, o);
        v2 += __shfl_down(v2, o);
    }
    if (lane == 0) {
        atomicAdd(&ws[3], v1);
        atomicAdd(&ws[4], v2);
        __threadfence();
        int old = atomicAdd((int*)(ws + 5), 1);
        if (old == NBLK - 1) {   // last block finalizes losses
            float lp = atomicAdd(&ws[3], 0.0f) * (1.0f / (float)BATCH);
            float lq = atomicAdd(&ws[4], 0.0f) * (1.0f / (float)BATCH);
            out[(size_t)(NSTEP + 1) * BATCH * 5] = lp;
            out[(size_t)(NSTEP + 1) * BATCH * 5 + 1] = lp + lq;
        }
    }
}

extern "C" void kernel_launch(void* const* d_in, const int* in_sizes, int n_in,
                              void* d_out, int out_size, void* d_ws, size_t ws_size,
                              hipStream_t stream) {
    const float* dw  = (const float*)d_in[0];
    const float* X0  = (const float*)d_in[1];
    const float* R0  = (const float*)d_in[2];
    const float* pW1 = (const float*)d_in[3];
    const float* pb1 = (const float*)d_in[4];
    const float* pW2 = (const float*)d_in[5];
    const float* pb2 = (const float*)d_in[6];
    const float* pW3 = (const float*)d_in[7];
    const float* pb3 = (const float*)d_in[8];
    const float* qW1 = (const float*)d_in[9];
    const float* qb1 = (const float*)d_in[10];
    const float* qW2 = (const float*)d_in[11];
    const float* qb2 = (const float*)d_in[12];
    const float* qW3 = (const float*)d_in[13];
    const float* qb3 = (const float*)d_in[14];
    float* out = (float*)d_out;
    float* ws  = (float*)d_ws;

    init_kernel<<<1, 256, 0, stream>>>(X0, R0, pW1, pb1, pW2, pb2, pW3, pb3,
                                       qW1, qb1, qW2, qb2, qW3, qb3, ws);
    step_kernel<<<NBLK, NT, 0, stream>>>(dw, X0, R0, qW1, qb1, qW2, qb2, qW3, qb3,
                                         ws, out);
}

// Round 4
// 209.597 us; speedup vs baseline: 2.2518x; 1.0924x over previous
//
#include <hip/hip_runtime.h>
#include <hip/hip_bf16.h>
#include <math.h>

#define NSTEP 100
#define BATCH 16384
#define MB 16            // samples per wave == MFMA M
#define NBLK (BATCH/MB)  // 1024 single-wave blocks -> 1 wave/SIMD
#define NT 64

#define C_ALPHA 0.05f
#define C_SIGMA 0.2f
#define C_THETA 0.3f
#define C_DT    0.01f
#define C_LOWER 1e-6f
#define C_PEN   100.0f
#define LOG2E   1.4426950408889634f
#define TSCALE  (2.0f * LOG2E)      // tanh(z) = 1 - 2/(exp2(TSCALE*z)+1)
#define CRT ( 0.015f * C_DT * LOG2E)
#define CRW ( 0.1f * LOG2E)
#define CPT (-0.095f * C_DT * LOG2E)
#define CPW (-0.3f * LOG2E)

typedef __attribute__((ext_vector_type(8))) short bf16x8;
typedef __attribute__((ext_vector_type(4))) float f32x4;

__device__ __forceinline__ float tanh_pre(float zs) {  // zs = TSCALE*z pre-folded
    float e = __builtin_amdgcn_exp2f(zs);
    return 1.0f - 2.0f * __builtin_amdgcn_rcpf(e + 1.0f);
}
__device__ __forceinline__ unsigned f2bf_u(float f) {  // RNE
    unsigned u = __float_as_uint(f);
    return (u + 0x7FFFu + ((u >> 16) & 1u)) >> 16;
}
__device__ __forceinline__ unsigned pack_bf16(float a, float b) {
    union { __hip_bfloat162 h; unsigned u; } cv;
    cv.h = __float22bfloat162_rn(make_float2(a, b));   // v_cvt_pk_bf16_f32
    return cv.u;
}
// sum across each 16-lane row via DPP row_ror butterfly; all lanes get the sum
__device__ __forceinline__ float dpp_row_sum16(float v) {
    int t;
    t = __builtin_amdgcn_update_dpp(0, __float_as_int(v), 0x128, 0xF, 0xF, true);
    v += __int_as_float(t);
    t = __builtin_amdgcn_update_dpp(0, __float_as_int(v), 0x124, 0xF, 0xF, true);
    v += __int_as_float(t);
    t = __builtin_amdgcn_update_dpp(0, __float_as_int(v), 0x122, 0xF, 0xF, true);
    v += __int_as_float(t);
    t = __builtin_amdgcn_update_dpp(0, __float_as_int(v), 0x121, 0xF, 0xF, true);
    v += __int_as_float(t);
    return v;
}

__global__ __launch_bounds__(NT, 1) void fused_kernel(
        const float* __restrict__ dw, const float* __restrict__ X0,
        const float* __restrict__ R0,
        const float* __restrict__ pW1, const float* __restrict__ pb1,
        const float* __restrict__ pW2, const float* __restrict__ pb2,
        const float* __restrict__ pW3, const float* __restrict__ pb3,
        const float* __restrict__ qW1, const float* __restrict__ qb1,
        const float* __restrict__ qW2, const float* __restrict__ qb2,
        const float* __restrict__ qW3, const float* __restrict__ qb3,
        float* __restrict__ ws, float* __restrict__ out) {
    __shared__ __align__(16) unsigned short sW2T[64 * 72];  // bf16 W2^T [n][k] *TSCALE
    __shared__ __align__(16) float sdw[MB * NSTEP];

    const int lane = threadIdx.x;          // single wave
    const int b0 = blockIdx.x * MB;
    const int l15 = lane & 15, quad = lane >> 4;

    // ---- stage dw (coalesced float4) and W2^T (bf16, pre-scaled) ----
    {
        const float4* g = (const float4*)(dw + (size_t)b0 * NSTEP);
        float4* s = (float4*)sdw;
        #pragma unroll
        for (int u = lane; u < MB * NSTEP / 4; u += NT) s[u] = g[u];
    }
    #pragma unroll 8
    for (int t = 0; t < 64; t++)
        sW2T[lane * 72 + t] = (unsigned short)f2bf_u(qW2[t * 64 + lane] * TSCALE);
    __syncthreads();

    // resident B fragments: 4 n-tiles x 2 k-steps (loop-invariant)
    bf16x8 Bf[4][2];
    #pragma unroll
    for (int nt = 0; nt < 4; nt++) {
        const unsigned short* r = &sW2T[(nt * 16 + l15) * 72 + quad * 8];
        Bf[nt][0] = *(const bf16x8*)r;
        Bf[nt][1] = *(const bf16x8*)(r + 32);
    }
    // layer-1 consts for this lane's 16 k's
    float tco[16], w1xs[16], w1rs[16], b1s[16];
    #pragma unroll
    for (int idx = 0; idx < 16; idx++) {
        int k = (idx < 8) ? (quad * 8 + idx) : (32 + quad * 8 + (idx - 8));
        tco[idx]  = qW1[k] * (2.0f * C_DT * TSCALE);
        w1xs[idx] = qW1[64 + k] * TSCALE;
        w1rs[idx] = qW1[128 + k] * TSCALE;
        b1s[idx]  = qb1[k] * TSCALE;
    }
    float b2v[4], w3v[4];
    #pragma unroll
    for (int nt = 0; nt < 4; nt++) {
        b2v[nt] = qb2[nt * 16 + l15] * TSCALE;
        w3v[nt] = qW3[nt * 16 + l15];
    }
    const float b3 = qb3[0];
    const float X0v = X0[0], R0s = R0[0];
    const int bperm_idx = (((l15 >> 2) * 16) + (l15 & 3)) * 4;

    // ---- p-net: p0, dp0 (one-time, shuffle MLP; all lanes end with values) ----
    float p0, dp0;
    {
        float pre = fmaf(pW1[64 + lane], X0v, fmaf(pW1[128 + lane], R0s, pb1[lane]));
        float h1 = tanh_pre(TSCALE * pre);
        float d1 = (1.0f - h1 * h1) * pW1[64 + lane];
        float a0 = pb2[lane], a1 = 0.f, a2 = 0.f, a3 = 0.f;
        float e0 = 0.f, e1 = 0.f, e2 = 0.f, e3 = 0.f;
        for (int i2 = 0; i2 < 64; i2 += 4) {
            float w0 = pW2[(i2 + 0) * 64 + lane];
            float w1 = pW2[(i2 + 1) * 64 + lane];
            float w2 = pW2[(i2 + 2) * 64 + lane];
            float w3 = pW2[(i2 + 3) * 64 + lane];
            a0 = fmaf(__shfl(h1, i2 + 0), w0, a0); e0 = fmaf(__shfl(d1, i2 + 0), w0, e0);
            a1 = fmaf(__shfl(h1, i2 + 1), w1, a1); e1 = fmaf(__shfl(d1, i2 + 1), w1, e1);
            a2 = fmaf(__shfl(h1, i2 + 2), w2, a2); e2 = fmaf(__shfl(d1, i2 + 2), w2, e2);
            a3 = fmaf(__shfl(h1, i2 + 3), w3, a3); e3 = fmaf(__shfl(d1, i2 + 3), w3, e3);
        }
        float pre2 = (a0 + a1) + (a2 + a3);
        float dpre2 = (e0 + e1) + (e2 + e3);
        float h2 = tanh_pre(TSCALE * pre2);
        float d2 = (1.0f - h2 * h2) * dpre2;
        float c1 = h2 * pW3[lane], c2 = d2 * pW3[lane];
        #pragma unroll
        for (int o = 1; o < 64; o <<= 1) {
            c1 += __shfl_xor(c1, o);
            c2 += __shfl_xor(c2, o);
        }
        p0 = c1 + pb3[0]; dp0 = c2;
    }

    // ---- q-net one-step evaluator: pi for sample l15, returned on ALL lanes ----
    auto qnet = [&](float fi, float xv, float rv) -> float {
        union { bf16x8 v; unsigned u[4]; } A0, A1;
        #pragma unroll
        for (int p = 0; p < 8; p++) {
            const int i0 = 2 * p, i1 = 2 * p + 1;
            float z0 = fmaf(w1rs[i0], rv, fmaf(w1xs[i0], xv, fmaf(tco[i0], fi, b1s[i0])));
            float z1 = fmaf(w1rs[i1], rv, fmaf(w1xs[i1], xv, fmaf(tco[i1], fi, b1s[i1])));
            unsigned pk = pack_bf16(tanh_pre(z0), tanh_pre(z1));
            if (p < 4) A0.u[p] = pk; else A1.u[p - 4] = pk;
        }
        f32x4 acc0 = {b2v[0], b2v[0], b2v[0], b2v[0]};
        f32x4 acc1 = {b2v[1], b2v[1], b2v[1], b2v[1]};
        f32x4 acc2 = {b2v[2], b2v[2], b2v[2], b2v[2]};
        f32x4 acc3 = {b2v[3], b2v[3], b2v[3], b2v[3]};
        acc0 = __builtin_amdgcn_mfma_f32_16x16x32_bf16(A0.v, Bf[0][0], acc0, 0, 0, 0);
        acc1 = __builtin_amdgcn_mfma_f32_16x16x32_bf16(A0.v, Bf[1][0], acc1, 0, 0, 0);
        acc2 = __builtin_amdgcn_mfma_f32_16x16x32_bf16(A0.v, Bf[2][0], acc2, 0, 0, 0);
        acc3 = __builtin_amdgcn_mfma_f32_16x16x32_bf16(A0.v, Bf[3][0], acc3, 0, 0, 0);
        acc0 = __builtin_amdgcn_mfma_f32_16x16x32_bf16(A1.v, Bf[0][1], acc0, 0, 0, 0);
        acc1 = __builtin_amdgcn_mfma_f32_16x16x32_bf16(A1.v, Bf[1][1], acc1, 0, 0, 0);
        acc2 = __builtin_amdgcn_mfma_f32_16x16x32_bf16(A1.v, Bf[2][1], acc2, 0, 0, 0);
        acc3 = __builtin_amdgcn_mfma_f32_16x16x32_bf16(A1.v, Bf[3][1], acc3, 0, 0, 0);
        f32x4 part;
        #pragma unroll
        for (int r = 0; r < 4; r++) {
            float sA = fmaf(tanh_pre(acc1[r]), w3v[1], tanh_pre(acc0[r]) * w3v[0]);
            float sB = fmaf(tanh_pre(acc3[r]), w3v[3], tanh_pre(acc2[r]) * w3v[2]);
            part[r] = dpp_row_sum16(sA + sB);   // row q: sums for samples 4q+r
        }
        float sLo = (lane & 1) ? part[1] : part[0];
        float sHi = (lane & 1) ? part[3] : part[2];
        float sel = (lane & 2) ? sHi : sLo;
        int g = __builtin_amdgcn_ds_bpermute(bperm_idx, __float_as_int(sel));
        return __int_as_float(g) + b3;
    };

    // ---- t=0 row + initial pi ----
    float x = X0v, Wsum = 0.0f, minx = X0v;
    float pi = qnet(0.0f, X0v, R0s);
    if (quad == 0) {
        size_t base = (size_t)(b0 + l15) * 5;
        out[base] = X0v; out[base + 1] = R0s; out[base + 2] = pi;
        out[base + 3] = -p0; out[base + 4] = -dp0;
    }

    float dw_next = sdw[l15 * NSTEP];
    #pragma unroll 1
    for (int i = 0; i < NSTEP - 1; i++) {
        const float fi = (float)(i + 1);
        float dwv = dw_next;
        dw_next = sdw[l15 * NSTEP + i + 1];
        float t = pi * C_SIGMA;
        x = fmaf(x, 1.0f + C_ALPHA * C_DT, fmaf(t, dwv, t * (C_THETA * C_DT)));
        minx = fminf(minx, x);
        Wsum += dwv;
        float R = R0s * __builtin_amdgcn_exp2f(fmaf(CRW, Wsum, CRT * fi));
        float pm = p0 * __builtin_amdgcn_exp2f(fmaf(CPW, Wsum, CPT * fi));
        float pin = qnet(fi, x, R);
        if (quad == 0) {
            size_t base = ((size_t)(i + 1) * BATCH + b0 + l15) * 5;
            out[base] = x; out[base + 1] = R; out[base + 2] = pin;
            out[base + 3] = -pm; out[base + 4] = -dp0;
        }
        pi = pin;
    }

    // ---- final step (pi not updated) + losses ----
    {
        float dwv = dw_next;
        float t = pi * C_SIGMA;
        x = fmaf(x, 1.0f + C_ALPHA * C_DT, fmaf(t, dwv, t * (C_THETA * C_DT)));
        minx = fminf(minx, x);
        Wsum += dwv;
        float Rf = R0s * __builtin_amdgcn_exp2f(fmaf(CRW, Wsum, CRT * (float)NSTEP));
        float pf = p0 * __builtin_amdgcn_exp2f(fmaf(CPW, Wsum, CPT * (float)NSTEP));
        if (quad == 0) {
            size_t base = ((size_t)NSTEP * BATCH + b0 + l15) * 5;
            out[base] = x; out[base + 1] = Rf; out[base + 2] = pi;
            out[base + 3] = -pf; out[base + 4] = -dp0;
        }
        float xc = fmaxf(x, C_LOWER);
        float ux = Rf * rsqrtf(xc);           // R * xc^(gamma-1), gamma=0.5
        float uval = 2.0f * Rf * sqrtf(xc);   // R * xc^gamma / gamma
        float d = fmaxf(C_LOWER - minx, 0.0f);
        float pen = C_PEN * d * d;
        float t1 = pf + ux;
        float v1 = dpp_row_sum16(t1 * t1 + pen);
        float v2 = dpp_row_sum16(-uval + pen);
        if (lane == 0) {
            atomicAdd(&ws[3], v1);
            atomicAdd(&ws[4], v2);
            __threadfence();
            int old = atomicAdd((int*)(ws + 5), 1);
            if (old == NBLK - 1) {   // last block finalizes losses
                float lp = atomicAdd(&ws[3], 0.0f) * (1.0f / (float)BATCH);
                float lq = atomicAdd(&ws[4], 0.0f) * (1.0f / (float)BATCH);
                out[(size_t)(NSTEP + 1) * BATCH * 5] = lp;
                out[(size_t)(NSTEP + 1) * BATCH * 5 + 1] = lp + lq;
            }
        }
    }
}

extern "C" void kernel_launch(void* const* d_in, const int* in_sizes, int n_in,
                              void* d_out, int out_size, void* d_ws, size_t ws_size,
                              hipStream_t stream) {
    const float* dw  = (const float*)d_in[0];
    const float* X0  = (const float*)d_in[1];
    const float* R0  = (const float*)d_in[2];
    const float* pW1 = (const float*)d_in[3];
    const float* pb1 = (const float*)d_in[4];
    const float* pW2 = (const float*)d_in[5];
    const float* pb2 = (const float*)d_in[6];
    const float* pW3 = (const float*)d_in[7];
    const float* pb3 = (const float*)d_in[8];
    const float* qW1 = (const float*)d_in[9];
    const float* qb1 = (const float*)d_in[10];
    const float* qW2 = (const float*)d_in[11];
    const float* qb2 = (const float*)d_in[12];
    const float* qW3 = (const float*)d_in[13];
    const float* qb3 = (const float*)d_in[14];
    float* out = (float*)d_out;
    float* ws  = (float*)d_ws;

    hipMemsetAsync(d_ws, 0, 64, stream);   // zero loss accumulators + block counter
    fused_kernel<<<NBLK, NT, 0, stream>>>(dw, X0, R0, pW1, pb1, pW2, pb2, pW3, pb3,
                                          qW1, qb1, qW2, qb2, qW3, qb3, ws, out);
}

// Round 5
// 208.929 us; speedup vs baseline: 2.2590x; 1.0032x over previous
//
#include <hip/hip_runtime.h>
#include <hip/hip_bf16.h>
#include <math.h>

#define NSTEP 100
#define BATCH 16384
#define MB 16            // samples per block == MFMA M
#define NBLK (BATCH/MB)  // 1024 blocks x 2 waves = 2048 waves -> 2/SIMD
#define NT 128

#define C_ALPHA 0.05f
#define C_SIGMA 0.2f
#define C_THETA 0.3f
#define C_DT    0.01f
#define C_LOWER 1e-6f
#define C_PEN   100.0f
#define LOG2E   1.4426950408889634f
#define TSCALE  (2.0f * LOG2E)      // tanh(z) = 1 - 2/(exp2(TSCALE*z)+1)
#define CRT ( 0.015f * C_DT * LOG2E)
#define CRW ( 0.1f * LOG2E)
#define CPT (-0.095f * C_DT * LOG2E)
#define CPW (-0.3f * LOG2E)

typedef __attribute__((ext_vector_type(8))) short bf16x8;
typedef __attribute__((ext_vector_type(4))) float f32x4;

__device__ __forceinline__ float tanh_pre(float zs) {  // zs = TSCALE*z pre-folded
    float e = __builtin_amdgcn_exp2f(zs);
    return 1.0f - 2.0f * __builtin_amdgcn_rcpf(e + 1.0f);
}
__device__ __forceinline__ unsigned f2bf_u(float f) {  // RNE
    unsigned u = __float_as_uint(f);
    return (u + 0x7FFFu + ((u >> 16) & 1u)) >> 16;
}
__device__ __forceinline__ unsigned pack_bf16(float a, float b) {
    union { __hip_bfloat162 h; unsigned u; } cv;
    cv.h = __float22bfloat162_rn(make_float2(a, b));   // v_cvt_pk_bf16_f32
    return cv.u;
}
// sum across each 16-lane row via DPP row_ror butterfly; all lanes get the sum
__device__ __forceinline__ float dpp_row_sum16(float v) {
    int t;
    t = __builtin_amdgcn_update_dpp(0, __float_as_int(v), 0x128, 0xF, 0xF, true);
    v += __int_as_float(t);
    t = __builtin_amdgcn_update_dpp(0, __float_as_int(v), 0x124, 0xF, 0xF, true);
    v += __int_as_float(t);
    t = __builtin_amdgcn_update_dpp(0, __float_as_int(v), 0x122, 0xF, 0xF, true);
    v += __int_as_float(t);
    t = __builtin_amdgcn_update_dpp(0, __float_as_int(v), 0x121, 0xF, 0xF, true);
    v += __int_as_float(t);
    return v;
}

__global__ __launch_bounds__(NT, 2) void fused_kernel(
        const float* __restrict__ dw, const float* __restrict__ X0,
        const float* __restrict__ R0,
        const float* __restrict__ pW1, const float* __restrict__ pb1,
        const float* __restrict__ pW2, const float* __restrict__ pb2,
        const float* __restrict__ pW3, const float* __restrict__ pb3,
        const float* __restrict__ qW1, const float* __restrict__ qb1,
        const float* __restrict__ qW2, const float* __restrict__ qb2,
        const float* __restrict__ qW3, const float* __restrict__ qb3,
        float* __restrict__ ws, float* __restrict__ out) {
    __shared__ __align__(16) unsigned short sW2T[64 * 72];  // bf16 W2^T [n][k] *TSCALE
    __shared__ __align__(16) float sdw[MB * NSTEP];
    __shared__ __align__(16) uint4 sA[2][2][64];   // [parity][kstep-owner wave][lane]
    __shared__ __align__(16) float sP[2][2][16];   // [parity][wave][sample]

    const int tid = threadIdx.x;
    const int lane = tid & 63;
    const int wv = tid >> 6;               // wave 0/1: n-half + kstep-half owner
    const int b0 = blockIdx.x * MB;
    const int l15 = lane & 15, quad = lane >> 4;

    // ---- stage dw (coalesced float4) and W2^T (bf16, pre-scaled) ----
    {
        const float4* g = (const float4*)(dw + (size_t)b0 * NSTEP);
        float4* s = (float4*)sdw;
        #pragma unroll
        for (int u = tid; u < MB * NSTEP / 4; u += NT) s[u] = g[u];
    }
    for (int u = tid; u < 4096; u += NT) {
        int k = u >> 6, n = u & 63;
        sW2T[n * 72 + k] = (unsigned short)f2bf_u(qW2[u] * TSCALE);
    }
    __syncthreads();

    // resident B fragments: this wave's 2 n-tiles x 2 k-steps
    bf16x8 Bf[2][2];
    #pragma unroll
    for (int t = 0; t < 2; t++) {
        const unsigned short* r = &sW2T[(wv * 32 + t * 16 + l15) * 72 + quad * 8];
        Bf[t][0] = *(const bf16x8*)r;
        Bf[t][1] = *(const bf16x8*)(r + 32);
    }
    // layer-1 consts: this wave's 8 k's (kstep = wv)
    float tco[8], w1xs[8], w1rs[8], b1s[8];
    #pragma unroll
    for (int j = 0; j < 8; j++) {
        int k = wv * 32 + quad * 8 + j;
        tco[j]  = qW1[k] * (2.0f * C_DT * TSCALE);
        w1xs[j] = qW1[64 + k] * TSCALE;
        w1rs[j] = qW1[128 + k] * TSCALE;
        b1s[j]  = qb1[k] * TSCALE;
    }
    float b2v[2], w3v[2];
    #pragma unroll
    for (int t = 0; t < 2; t++) {
        b2v[t] = qb2[wv * 32 + t * 16 + l15] * TSCALE;
        w3v[t] = qW3[wv * 32 + t * 16 + l15];
    }
    const float b3 = qb3[0];
    const float X0v = X0[0], R0s = R0[0];

    // ---- p-net: p0, dp0 (one-time; computed redundantly per wave) ----
    float p0, dp0;
    {
        float pre = fmaf(pW1[64 + lane], X0v, fmaf(pW1[128 + lane], R0s, pb1[lane]));
        float h1 = tanh_pre(TSCALE * pre);
        float d1 = (1.0f - h1 * h1) * pW1[64 + lane];
        float a0 = pb2[lane], a1 = 0.f, a2 = 0.f, a3 = 0.f;
        float e0 = 0.f, e1 = 0.f, e2 = 0.f, e3 = 0.f;
        for (int i2 = 0; i2 < 64; i2 += 4) {
            float w0 = pW2[(i2 + 0) * 64 + lane];
            float w1 = pW2[(i2 + 1) * 64 + lane];
            float w2 = pW2[(i2 + 2) * 64 + lane];
            float w3 = pW2[(i2 + 3) * 64 + lane];
            a0 = fmaf(__shfl(h1, i2 + 0), w0, a0); e0 = fmaf(__shfl(d1, i2 + 0), w0, e0);
            a1 = fmaf(__shfl(h1, i2 + 1), w1, a1); e1 = fmaf(__shfl(d1, i2 + 1), w1, e1);
            a2 = fmaf(__shfl(h1, i2 + 2), w2, a2); e2 = fmaf(__shfl(d1, i2 + 2), w2, e2);
            a3 = fmaf(__shfl(h1, i2 + 3), w3, a3); e3 = fmaf(__shfl(d1, i2 + 3), w3, e3);
        }
        float pre2 = (a0 + a1) + (a2 + a3);
        float dpre2 = (e0 + e1) + (e2 + e3);
        float h2 = tanh_pre(TSCALE * pre2);
        float d2 = (1.0f - h2 * h2) * dpre2;
        float c1 = h2 * pW3[lane], c2 = d2 * pW3[lane];
        #pragma unroll
        for (int o = 1; o < 64; o <<= 1) {
            c1 += __shfl_xor(c1, o);
            c2 += __shfl_xor(c2, o);
        }
        p0 = c1 + pb3[0]; dp0 = c2;
    }

    // ---- cooperative q-net: 2 waves split n & k; pi returned on ALL lanes ----
    auto qnet = [&](int par, float fi, float xv, float rv) -> float {
        union { uint4 u4; bf16x8 v; unsigned u[4]; } Aloc, Aoth;
        #pragma unroll
        for (int p = 0; p < 4; p++) {
            const int i0 = 2 * p, i1 = 2 * p + 1;
            float z0 = fmaf(w1rs[i0], rv, fmaf(w1xs[i0], xv, fmaf(tco[i0], fi, b1s[i0])));
            float z1 = fmaf(w1rs[i1], rv, fmaf(w1xs[i1], xv, fmaf(tco[i1], fi, b1s[i1])));
            Aloc.u[p] = pack_bf16(tanh_pre(z0), tanh_pre(z1));
        }
        sA[par][wv][lane] = Aloc.u4;
        __syncthreads();                       // B1: A halves exchanged
        Aoth.u4 = sA[par][1 - wv][lane];
        bf16x8 A0 = (wv == 0) ? Aloc.v : Aoth.v;   // kstep 0 frag
        bf16x8 A1 = (wv == 0) ? Aoth.v : Aloc.v;   // kstep 1 frag
        f32x4 acc0 = {b2v[0], b2v[0], b2v[0], b2v[0]};
        f32x4 acc1 = {b2v[1], b2v[1], b2v[1], b2v[1]};
        acc0 = __builtin_amdgcn_mfma_f32_16x16x32_bf16(A0, Bf[0][0], acc0, 0, 0, 0);
        acc1 = __builtin_amdgcn_mfma_f32_16x16x32_bf16(A0, Bf[1][0], acc1, 0, 0, 0);
        acc0 = __builtin_amdgcn_mfma_f32_16x16x32_bf16(A1, Bf[0][1], acc0, 0, 0, 0);
        acc1 = __builtin_amdgcn_mfma_f32_16x16x32_bf16(A1, Bf[1][1], acc1, 0, 0, 0);
        f32x4 part;
        #pragma unroll
        for (int r = 0; r < 4; r++)
            part[r] = dpp_row_sum16(
                fmaf(tanh_pre(acc1[r]), w3v[1], tanh_pre(acc0[r]) * w3v[0]));
        if (l15 == 0) *(f32x4*)&sP[par][wv][quad * 4] = part;  // samples 4q+r
        __syncthreads();                       // B2: partials exchanged
        return sP[par][0][l15] + sP[par][1][l15] + b3;
    };

    // ---- t=0 row + initial pi ----
    float x = X0v, Wsum = 0.0f, minx = X0v;
    float pi = qnet(0, 0.0f, X0v, R0s);
    if (wv == 1 && quad == 0) {
        size_t base = (size_t)(b0 + l15) * 5;
        out[base] = X0v; out[base + 1] = R0s; out[base + 2] = pi;
        out[base + 3] = -p0; out[base + 4] = -dp0;
    }

    float dw_next = sdw[l15 * NSTEP];
    #pragma unroll 1
    for (int i = 0; i < NSTEP - 1; i++) {
        const float fi = (float)(i + 1);
        float dwv = dw_next;
        dw_next = sdw[l15 * NSTEP + i + 1];
        float t = pi * C_SIGMA;
        x = fmaf(x, 1.0f + C_ALPHA * C_DT, fmaf(t, dwv, t * (C_THETA * C_DT)));
        minx = fminf(minx, x);
        Wsum += dwv;
        float R = R0s * __builtin_amdgcn_exp2f(fmaf(CRW, Wsum, CRT * fi));
        float pm = p0 * __builtin_amdgcn_exp2f(fmaf(CPW, Wsum, CPT * fi));
        float pin = qnet((i + 1) & 1, fi, x, R);
        if (wv == 1 && quad == 0) {
            size_t base = ((size_t)(i + 1) * BATCH + b0 + l15) * 5;
            out[base] = x; out[base + 1] = R; out[base + 2] = pin;
            out[base + 3] = -pm; out[base + 4] = -dp0;
        }
        pi = pin;
    }

    // ---- final step (pi not updated) + losses ----
    {
        float dwv = dw_next;
        float t = pi * C_SIGMA;
        x = fmaf(x, 1.0f + C_ALPHA * C_DT, fmaf(t, dwv, t * (C_THETA * C_DT)));
        minx = fminf(minx, x);
        Wsum += dwv;
        float Rf = R0s * __builtin_amdgcn_exp2f(fmaf(CRW, Wsum, CRT * (float)NSTEP));
        float pf = p0 * __builtin_amdgcn_exp2f(fmaf(CPW, Wsum, CPT * (float)NSTEP));
        if (wv == 1 && quad == 0) {
            size_t base = ((size_t)NSTEP * BATCH + b0 + l15) * 5;
            out[base] = x; out[base + 1] = Rf; out[base + 2] = pi;
            out[base + 3] = -pf; out[base + 4] = -dp0;
        }
        if (wv == 0) {
            float xc = fmaxf(x, C_LOWER);
            float ux = Rf * rsqrtf(xc);           // R * xc^(gamma-1), gamma=0.5
            float uval = 2.0f * Rf * sqrtf(xc);   // R * xc^gamma / gamma
            float d = fmaxf(C_LOWER - minx, 0.0f);
            float pen = C_PEN * d * d;
            float t1 = pf + ux;
            float v1 = dpp_row_sum16(t1 * t1 + pen);
            float v2 = dpp_row_sum16(-uval + pen);
            if (lane == 0) {
                atomicAdd(&ws[3], v1);
                atomicAdd(&ws[4], v2);
                __threadfence();
                int old = atomicAdd((int*)(ws + 5), 1);
                if (old == NBLK - 1) {   // last block finalizes losses
                    float lp = atomicAdd(&ws[3], 0.0f) * (1.0f / (float)BATCH);
                    float lq = atomicAdd(&ws[4], 0.0f) * (1.0f / (float)BATCH);
                    out[(size_t)(NSTEP + 1) * BATCH * 5] = lp;
                    out[(size_t)(NSTEP + 1) * BATCH * 5 + 1] = lp + lq;
                }
            }
        }
    }
}

extern "C" void kernel_launch(void* const* d_in, const int* in_sizes, int n_in,
                              void* d_out, int out_size, void* d_ws, size_t ws_size,
                              hipStream_t stream) {
    const float* dw  = (const float*)d_in[0];
    const float* X0  = (const float*)d_in[1];
    const float* R0  = (const float*)d_in[2];
    const float* pW1 = (const float*)d_in[3];
    const float* pb1 = (const float*)d_in[4];
    const float* pW2 = (const float*)d_in[5];
    const float* pb2 = (const float*)d_in[6];
    const float* pW3 = (const float*)d_in[7];
    const float* pb3 = (const float*)d_in[8];
    const float* qW1 = (const float*)d_in[9];
    const float* qb1 = (const float*)d_in[10];
    const float* qW2 = (const float*)d_in[11];
    const float* qb2 = (const float*)d_in[12];
    const float* qW3 = (const float*)d_in[13];
    const float* qb3 = (const float*)d_in[14];
    float* out = (float*)d_out;
    float* ws  = (float*)d_ws;

    hipMemsetAsync(d_ws, 0, 64, stream);   // zero loss accumulators + block counter
    fused_kernel<<<NBLK, NT, 0, stream>>>(dw, X0, R0, pW1, pb1, pW2, pb2, pW3, pb3,
                                          qW1, qb1, qW2, qb2, qW3, qb3, ws, out);
}